// Round 1
// baseline (788.049 us; speedup 1.0000x reference)
//
#include <hip/hip_runtime.h>
#include <hip/hip_bf16.h>
#include <cstdint>

#define T_DIM 2048
#define C_DIM 256
#define BS 8
#define NPTS (BS * T_DIM)
#define KNB 10

// ---------------- transpose: x(b,c,t) -> feat[(b*T+t)*C + c] ----------------
__global__ __launch_bounds__(256) void k_transpose(const float* __restrict__ x,
                                                   float* __restrict__ feat) {
  __shared__ float tile[32][33];
  int b = blockIdx.z;
  int t0 = blockIdx.x * 32;
  int c0 = blockIdx.y * 32;
  int tx = threadIdx.x & 31, ty = threadIdx.x >> 5;
  const float* xb = x + (size_t)b * C_DIM * T_DIM;
#pragma unroll
  for (int r = 0; r < 4; ++r) {
    int c = c0 + ty + 8 * r;
    tile[ty + 8 * r][tx] = xb[(size_t)c * T_DIM + t0 + tx];
  }
  __syncthreads();
#pragma unroll
  for (int r = 0; r < 4; ++r) {
    int t = t0 + ty + 8 * r;
    feat[((size_t)b * T_DIM + t) * C_DIM + c0 + tx] = tile[tx][ty + 8 * r];
  }
}

// ---------------- sq[n] = sum_c feat[n,c]^2 ----------------
__global__ __launch_bounds__(256) void k_sq(const float* __restrict__ feat,
                                            float* __restrict__ sq) {
  int n = blockIdx.x * 4 + (threadIdx.x >> 6);
  int lane = threadIdx.x & 63;
  const float* row = feat + (size_t)n * C_DIM;
  float s = 0.f;
#pragma unroll
  for (int i = 0; i < 4; ++i) {
    float v = row[lane + 64 * i];
    s = fmaf(v, v, s);
  }
#pragma unroll
  for (int d = 1; d < 64; d <<= 1) s += __shfl_xor(s, d, 64);
  if (lane == 0) sq[n] = s;
}

// ---------------- generic C = A * B^T (K=256), optional row shift+mask, optional accumulate ----------------
// A: M x 256 row-major (lda), Bm: N x 256 row-major (ldb), C: M x N (ldc)
// shift != 0: A row m reads A[(m+shift)] but is zero if ((m & 2047) + shift) outside [0,2048)
__global__ __launch_bounds__(256) void k_gemm_abt(const float* __restrict__ A, int lda,
                                                  const float* __restrict__ Bm, int ldb,
                                                  float* __restrict__ C, int ldc,
                                                  int shift, int accum) {
  __shared__ float As[16][128];
  __shared__ float Bs[16][128];
  int tid = threadIdx.x;
  int m0 = blockIdx.y * 128;
  int n0 = blockIdx.x * 128;
  int lrow = tid >> 1;
  int lk = (tid & 1) * 8;
  int tx = tid & 15, ty = tid >> 4;
  float acc[8][8];
#pragma unroll
  for (int i = 0; i < 8; ++i)
#pragma unroll
    for (int j = 0; j < 8; ++j) acc[i][j] = 0.f;

  for (int k0 = 0; k0 < 256; k0 += 16) {
    float4 v0 = {0, 0, 0, 0}, v1 = {0, 0, 0, 0};
    int gm = m0 + lrow;
    bool valid = true;
    if (shift != 0) {
      int t = (gm & (T_DIM - 1)) + shift;
      valid = ((unsigned)t < (unsigned)T_DIM);
    }
    if (valid) {
      const float* ap = A + (size_t)(gm + shift) * lda + k0 + lk;
      v0 = *(const float4*)ap;
      v1 = *(const float4*)(ap + 4);
    }
    As[lk + 0][lrow] = v0.x; As[lk + 1][lrow] = v0.y;
    As[lk + 2][lrow] = v0.z; As[lk + 3][lrow] = v0.w;
    As[lk + 4][lrow] = v1.x; As[lk + 5][lrow] = v1.y;
    As[lk + 6][lrow] = v1.z; As[lk + 7][lrow] = v1.w;
    {
      const float* bp = Bm + (size_t)(n0 + lrow) * ldb + k0 + lk;
      float4 w0 = *(const float4*)bp;
      float4 w1 = *(const float4*)(bp + 4);
      Bs[lk + 0][lrow] = w0.x; Bs[lk + 1][lrow] = w0.y;
      Bs[lk + 2][lrow] = w0.z; Bs[lk + 3][lrow] = w0.w;
      Bs[lk + 4][lrow] = w1.x; Bs[lk + 5][lrow] = w1.y;
      Bs[lk + 6][lrow] = w1.z; Bs[lk + 7][lrow] = w1.w;
    }
    __syncthreads();
#pragma unroll
    for (int kk = 0; kk < 16; ++kk) {
      float4 a0 = *(const float4*)&As[kk][ty * 4];
      float4 a1 = *(const float4*)&As[kk][64 + ty * 4];
      float4 b0 = *(const float4*)&Bs[kk][tx * 4];
      float4 b1 = *(const float4*)&Bs[kk][64 + tx * 4];
      float av[8] = {a0.x, a0.y, a0.z, a0.w, a1.x, a1.y, a1.z, a1.w};
      float bv[8] = {b0.x, b0.y, b0.z, b0.w, b1.x, b1.y, b1.z, b1.w};
#pragma unroll
      for (int i = 0; i < 8; ++i)
#pragma unroll
        for (int j = 0; j < 8; ++j) acc[i][j] = fmaf(av[i], bv[j], acc[i][j]);
    }
    __syncthreads();
  }
#pragma unroll
  for (int r = 0; r < 8; ++r) {
    int ml = (r < 4) ? (ty * 4 + r) : (64 + ty * 4 + (r - 4));
    float* crow = C + (size_t)(m0 + ml) * ldc + n0;
#pragma unroll
    for (int half = 0; half < 2; ++half) {
      float4 val;
      val.x = acc[r][half * 4 + 0];
      val.y = acc[r][half * 4 + 1];
      val.z = acc[r][half * 4 + 2];
      val.w = acc[r][half * 4 + 3];
      float4* cp = (float4*)&crow[half * 64 + tx * 4];
      if (accum) {
        float4 o = *cp;
        val.x += o.x; val.y += o.y; val.z += o.z; val.w += o.w;
      }
      *cp = val;
    }
  }
}

// ---------------- per-row top-10 of dif = sq_i + sq_j - 2*gram[i][j] ----------------
// one wave per row; per-lane sorted top-10 then 10-round wave-min merge.
__global__ __launch_bounds__(256) void k_topk(const float* __restrict__ gram,
                                              const float* __restrict__ sqb,
                                              int* __restrict__ idxo,
                                              float* __restrict__ wo) {
  int row = blockIdx.x * 4 + (threadIdx.x >> 6);
  int lane = threadIdx.x & 63;
  float sqi = sqb[row];
  const float* g = gram + (size_t)row * T_DIM;
  unsigned long long a0 = ~0ull, a1 = ~0ull, a2 = ~0ull, a3 = ~0ull, a4 = ~0ull,
                     a5 = ~0ull, a6 = ~0ull, a7 = ~0ull, a8 = ~0ull, a9 = ~0ull;
  for (int j = lane; j < T_DIM; j += 64) {
    float dif = sqi + sqb[j] - 2.0f * g[j];
    unsigned u = __float_as_uint(dif);
    u = (u & 0x80000000u) ? ~u : (u | 0x80000000u);
    unsigned long long key = ((unsigned long long)u << 32) | (unsigned)j;
    if (key < a9) {
      a9 = key;
      unsigned long long t;
      if (a9 < a8) { t = a8; a8 = a9; a9 = t; }
      if (a8 < a7) { t = a7; a7 = a8; a8 = t; }
      if (a7 < a6) { t = a6; a6 = a7; a7 = t; }
      if (a6 < a5) { t = a5; a5 = a6; a6 = t; }
      if (a5 < a4) { t = a4; a4 = a5; a5 = t; }
      if (a4 < a3) { t = a3; a3 = a4; a4 = t; }
      if (a3 < a2) { t = a2; a2 = a3; a3 = t; }
      if (a2 < a1) { t = a1; a1 = a2; a2 = t; }
      if (a1 < a0) { t = a0; a0 = a1; a1 = t; }
    }
  }
#pragma unroll
  for (int s = 0; s < KNB; ++s) {
    unsigned long long h = a0;
    unsigned long long m = h;
#pragma unroll
    for (int d = 1; d < 64; d <<= 1) {
      unsigned long long o = __shfl_xor(m, d, 64);
      m = (o < m) ? o : m;
    }
    unsigned long long bal = __ballot(h == m);
    int leader = (int)__builtin_ctzll(bal);
    if (lane == leader) {
      a0 = a1; a1 = a2; a2 = a3; a3 = a4; a4 = a5;
      a5 = a6; a6 = a7; a7 = a8; a8 = a9; a9 = ~0ull;
    }
    if (lane == 0) {
      int j = (int)(unsigned)(m & 0xffffffffull);
      unsigned su = (unsigned)(m >> 32);
      unsigned bits = (su & 0x80000000u) ? (su & 0x7fffffffu) : ~su;
      float dif = __uint_as_float(bits);
      float sqj = sqb[j];
      float num = 0.5f * (sqi + sqj - dif);
      float w = num / (sqrtf(sqi) * sqrtf(sqj));
      idxo[row * KNB + s] = j;
      wo[row * KNB + s] = w;
    }
  }
}

// ---------------- gmax[n,o] = max_k (B[m_k,o] + A[n,o] + mlp_b[o]) * w[n,k] ----------------
__global__ __launch_bounds__(256) void k_gmax(const float* __restrict__ Bbuf,
                                              const float* __restrict__ Abuf,
                                              const float* __restrict__ mlp_b,
                                              const int* __restrict__ idxo,
                                              const float* __restrict__ wo,
                                              float* __restrict__ gmax) {
  int n = blockIdx.x;
  int o = threadIdx.x;
  __shared__ int sj[KNB];
  __shared__ float sw[KNB];
  if (o < KNB) {
    sj[o] = (n & ~(T_DIM - 1)) + idxo[n * KNB + o];  // per-batch -> global row
    sw[o] = wo[n * KNB + o];
  }
  __syncthreads();
  float a = Abuf[(size_t)n * C_DIM + o] + mlp_b[o];
  float mx = -3.4e38f;
#pragma unroll
  for (int k = 0; k < KNB; ++k) {
    float v = (Bbuf[(size_t)sj[k] * C_DIM + o] + a) * sw[k];
    mx = fmaxf(mx, v);
  }
  gmax[(size_t)n * C_DIM + o] = mx;
}

// ---------------- out = maxpool2(relu(conv + cb + gmax)), (n,o) -> (b,c,t/2) ----------------
__global__ __launch_bounds__(256) void k_final(const float* __restrict__ convb,
                                               const float* __restrict__ gmax,
                                               const float* __restrict__ cb,
                                               float* __restrict__ out) {
  __shared__ float tile[32][33];
  int b = blockIdx.z;
  int c0 = blockIdx.y * 32;
  int t20 = blockIdx.x * 32;
  int tx = threadIdx.x & 31, ty = threadIdx.x >> 5;
#pragma unroll
  for (int r = 0; r < 4; ++r) {
    int t2 = t20 + ty + 8 * r;
    size_t n = ((size_t)b * T_DIM + 2 * t2) * C_DIM + c0 + tx;
    float bias = cb[c0 + tx];
    float v0 = convb[n] + gmax[n] + bias;
    float v1 = convb[n + C_DIM] + gmax[n + C_DIM] + bias;
    v0 = fmaxf(v0, 0.f);
    v1 = fmaxf(v1, 0.f);
    tile[ty + 8 * r][tx] = fmaxf(v0, v1);
  }
  __syncthreads();
#pragma unroll
  for (int r = 0; r < 4; ++r) {
    int c = c0 + ty + 8 * r;
    out[((size_t)b * C_DIM + c) * (T_DIM / 2) + t20 + tx] = tile[tx][ty + 8 * r];
  }
}

// ---------------- repack conv_w (O,I,3) -> wk[k][o][i] contiguous in i ----------------
__global__ void k_repack(const float* __restrict__ cw, float* __restrict__ wk) {
  int i = blockIdx.x * 256 + threadIdx.x;
  if (i < 3 * C_DIM * C_DIM) {
    int k = i / (C_DIM * C_DIM);
    int rem = i - k * (C_DIM * C_DIM);
    int o = rem >> 8;
    int ii = rem & 255;
    wk[i] = cw[(size_t)o * 768 + ii * 3 + k];
  }
}

extern "C" void kernel_launch(void* const* d_in, const int* in_sizes, int n_in,
                              void* d_out, int out_size, void* d_ws, size_t ws_size,
                              hipStream_t stream) {
  const float* x = (const float*)d_in[0];
  // d_in[1] = num_frms (unused by reference)
  const float* conv_w = (const float*)d_in[2];
  const float* conv_b = (const float*)d_in[3];
  const float* mlp_w = (const float*)d_in[4];
  const float* mlp_b = (const float*)d_in[5];
  float* out = (float*)d_out;

  char* ws = (char*)d_ws;
  size_t off = 0;
  auto alloc = [&](size_t bytes) -> void* {
    void* p = ws + off;
    off += (bytes + 255) & ~(size_t)255;
    return p;
  };
  float* feat = (float*)alloc((size_t)NPTS * C_DIM * 4);
  float* sq = (float*)alloc((size_t)NPTS * 4);
  float* Bbuf = (float*)alloc((size_t)NPTS * C_DIM * 4);
  float* Abuf = (float*)alloc((size_t)NPTS * C_DIM * 4);
  float* convbf = (float*)alloc((size_t)NPTS * C_DIM * 4);
  float* gram = (float*)alloc((size_t)T_DIM * T_DIM * 4);  // reused later as gmax
  int* idxb = (int*)alloc((size_t)NPTS * KNB * 4);
  float* wb = (float*)alloc((size_t)NPTS * KNB * 4);
  float* wkbuf = (float*)alloc((size_t)3 * C_DIM * C_DIM * 4);
  float* gmaxb = gram;

  k_repack<<<dim3((3 * C_DIM * C_DIM + 255) / 256), 256, 0, stream>>>(conv_w, wkbuf);
  k_transpose<<<dim3(T_DIM / 32, C_DIM / 32, BS), 256, 0, stream>>>(x, feat);
  k_sq<<<dim3(NPTS / 4), 256, 0, stream>>>(feat, sq);

  for (int b = 0; b < BS; ++b) {
    const float* fb = feat + (size_t)b * T_DIM * C_DIM;
    k_gemm_abt<<<dim3(T_DIM / 128, T_DIM / 128), 256, 0, stream>>>(
        fb, C_DIM, fb, C_DIM, gram, T_DIM, 0, 0);
    k_topk<<<dim3(T_DIM / 4), 256, 0, stream>>>(
        gram, sq + (size_t)b * T_DIM,
        idxb + (size_t)b * T_DIM * KNB, wb + (size_t)b * T_DIM * KNB);
  }

  // MLP halves: B = feat . mlp_w[:, :C]^T ; A = feat . mlp_w[:, C:]^T
  k_gemm_abt<<<dim3(C_DIM / 128, NPTS / 128), 256, 0, stream>>>(
      feat, C_DIM, mlp_w, 2 * C_DIM, Bbuf, C_DIM, 0, 0);
  k_gemm_abt<<<dim3(C_DIM / 128, NPTS / 128), 256, 0, stream>>>(
      feat, C_DIM, mlp_w + C_DIM, 2 * C_DIM, Abuf, C_DIM, 0, 0);

  // conv as 3 shifted GEMMs accumulating into convbf
  for (int k = 0; k < 3; ++k) {
    k_gemm_abt<<<dim3(C_DIM / 128, NPTS / 128), 256, 0, stream>>>(
        feat, C_DIM, wkbuf + (size_t)k * C_DIM * C_DIM, C_DIM, convbf, C_DIM,
        k - 1, (k > 0) ? 1 : 0);
  }

  k_gmax<<<dim3(NPTS), 256, 0, stream>>>(Bbuf, Abuf, mlp_b, idxb, wb, gmaxb);
  k_final<<<dim3((T_DIM / 2) / 32, C_DIM / 32, BS), 256, 0, stream>>>(
      convbf, gmaxb, conv_b, out);
}

// Round 2
// 253.048 us; speedup vs baseline: 3.1142x; 3.1142x over previous
//
#include <hip/hip_runtime.h>
#include <hip/hip_bf16.h>
#include <cstdint>

#define T_DIM 2048
#define C_DIM 256
#define BS 8
#define NPTS (BS * T_DIM)
#define KNB 10

typedef __bf16 bf16x8 __attribute__((ext_vector_type(8)));
typedef float f32x4 __attribute__((ext_vector_type(4)));

#define AS1 __attribute__((address_space(1)))
#define AS3 __attribute__((address_space(3)))

__device__ __forceinline__ unsigned short f2bf_rn(float f) {
  unsigned u = __float_as_uint(f);
  unsigned r = (u + 0x7FFFu + ((u >> 16) & 1u)) >> 16;
  return (unsigned short)r;
}
__device__ __forceinline__ float bfbits2f(unsigned short h) {
  return __uint_as_float((unsigned)h << 16);
}
__device__ __forceinline__ __bf16 bfbits(unsigned short h) {
  return __builtin_bit_cast(__bf16, h);
}

// ---- stage a 128x64 bf16 tile into XOR-swizzled LDS via global_load_lds ----
// LDS layout: byte(row, colbyte) = row*128 + (colbyte ^ ((row&7)<<4)).
// global_load_lds writes linearly (base + lane*16), so the SOURCE address is
// pre-swizzled: lane l covers row (q*8 + (l>>3)), col elems 8*((l&7)^(l>>3)).
__device__ __forceinline__ void stage_tile(const __bf16* __restrict__ src, size_t row0,
                                           int ld, int k0, __bf16* lds, int w, int l) {
  int kofs = ((l & 7) ^ (l >> 3)) * 8;
  const __bf16* g0 = src + (row0 + (size_t)(l >> 3)) * ld + k0 + kofs;
  __bf16* lbase = lds + (size_t)(w * 4) * 512;
#pragma unroll
  for (int q4 = 0; q4 < 4; ++q4) {
    __builtin_amdgcn_global_load_lds((AS1 void*)(g0 + (size_t)(w * 4 + q4) * 8 * ld),
                                     (AS3 void*)(lbase + q4 * 512), 16, 0, 0);
  }
}

// conv im2col staging: K=768 = 3 taps x 256; row source shifted by tap-1,
// batch-boundary rows read a zero page instead (per-lane address select).
__device__ __forceinline__ void stage_tile_conv(const __bf16* __restrict__ src, int m0,
                                                int k0in, const __bf16* __restrict__ zp,
                                                __bf16* lds, int w, int l) {
  int tap = k0in >> 8;
  int kshift = tap - 1;
  int k0 = k0in & 255;
  int kofs = ((l & 7) ^ (l >> 3)) * 8;
  int mb = m0 & (T_DIM - 1);
#pragma unroll
  for (int q4 = 0; q4 < 4; ++q4) {
    int q = w * 4 + q4;
    int row = q * 8 + (l >> 3);
    int t = mb + row + kshift;
    const __bf16* g = ((unsigned)t < (unsigned)T_DIM)
                          ? (src + (size_t)(m0 + row + kshift) * C_DIM + k0 + kofs)
                          : (zp + kofs);
    __builtin_amdgcn_global_load_lds((AS1 void*)g, (AS3 void*)(lds + q * 512), 16, 0, 0);
  }
}

// fragment read for mfma_f32_16x16x32_bf16: lane holds row (l&15), k-block (l>>4)*8
__device__ __forceinline__ bf16x8 read_frag(const __bf16* lds, int t16, int ks, int l) {
  int row = t16 * 16 + (l & 15);
  int kb = ks * 64 + ((l >> 4) << 4);
  int byte = row * 128 + (kb ^ ((row & 7) << 4));
  return *(const bf16x8*)((const char*)lds + byte);
}

// ---------------- transpose + hi/lo bf16 split: x(b,c,t) -> Fh/Fl[(b*T+t)*C+c] ----------------
__global__ __launch_bounds__(256) void k_transpose_split(const float* __restrict__ x,
                                                         __bf16* __restrict__ Fh,
                                                         __bf16* __restrict__ Fl) {
  __shared__ float tile[32][33];
  int b = blockIdx.z;
  int t0 = blockIdx.x * 32;
  int c0 = blockIdx.y * 32;
  int tx = threadIdx.x & 31, ty = threadIdx.x >> 5;
  const float* xb = x + (size_t)b * C_DIM * T_DIM;
#pragma unroll
  for (int r = 0; r < 4; ++r) {
    int c = c0 + ty + 8 * r;
    tile[ty + 8 * r][tx] = xb[(size_t)c * T_DIM + t0 + tx];
  }
  __syncthreads();
#pragma unroll
  for (int r = 0; r < 4; ++r) {
    int t = t0 + ty + 8 * r;
    float v = tile[tx][ty + 8 * r];
    unsigned short hb = f2bf_rn(v);
    float lo = v - bfbits2f(hb);
    size_t o = ((size_t)b * T_DIM + t) * C_DIM + c0 + tx;
    Fh[o] = bfbits(hb);
    Fl[o] = bfbits(f2bf_rn(lo));
  }
}

// ---------------- sq[n] = sum_c (hi+lo)^2 ----------------
__global__ __launch_bounds__(256) void k_sq(const __bf16* __restrict__ Fh,
                                            const __bf16* __restrict__ Fl,
                                            float* __restrict__ sq) {
  int n = blockIdx.x * 4 + (threadIdx.x >> 6);
  int lane = threadIdx.x & 63;
  ushort4 hv = ((const ushort4*)Fh)[(size_t)n * 64 + lane];
  ushort4 lv = ((const ushort4*)Fl)[(size_t)n * 64 + lane];
  float s = 0.f;
  {
    float v;
    v = bfbits2f(hv.x) + bfbits2f(lv.x); s = fmaf(v, v, s);
    v = bfbits2f(hv.y) + bfbits2f(lv.y); s = fmaf(v, v, s);
    v = bfbits2f(hv.z) + bfbits2f(lv.z); s = fmaf(v, v, s);
    v = bfbits2f(hv.w) + bfbits2f(lv.w); s = fmaf(v, v, s);
  }
#pragma unroll
  for (int d = 1; d < 64; d <<= 1) s += __shfl_xor(s, d, 64);
  if (lane == 0) sq[n] = s;
}

// ---------------- Gram via split-bf16 MFMA: gram = F.F^T (per batch) ----------------
__global__ __launch_bounds__(256, 2) void k_gram(const __bf16* __restrict__ Fh,
                                                 const __bf16* __restrict__ Fl,
                                                 float* __restrict__ gram, int bg) {
  __shared__ __bf16 Ah[128 * 64], Al[128 * 64], Bh[128 * 64], Bl[128 * 64];
  int lb = blockIdx.z;
  size_t base = (size_t)(bg + lb) * T_DIM;
  int m0 = blockIdx.y * 128, n0 = blockIdx.x * 128;
  int tid = threadIdx.x, w = tid >> 6, l = tid & 63;
  int wr = w >> 1, wc = w & 1;
  f32x4 acc[4][4];
#pragma unroll
  for (int i = 0; i < 4; ++i)
#pragma unroll
    for (int j = 0; j < 4; ++j) acc[i][j] = {0.f, 0.f, 0.f, 0.f};

  for (int k0 = 0; k0 < C_DIM; k0 += 64) {
    stage_tile(Fh, base + m0, C_DIM, k0, Ah, w, l);
    stage_tile(Fl, base + m0, C_DIM, k0, Al, w, l);
    stage_tile(Fh, base + n0, C_DIM, k0, Bh, w, l);
    stage_tile(Fl, base + n0, C_DIM, k0, Bl, w, l);
    __syncthreads();
#pragma unroll
    for (int ks = 0; ks < 2; ++ks) {
      bf16x8 ah[4], bh[4], x[4];
#pragma unroll
      for (int i = 0; i < 4; ++i) ah[i] = read_frag(Ah, wr * 4 + i, ks, l);
#pragma unroll
      for (int j = 0; j < 4; ++j) bh[j] = read_frag(Bh, wc * 4 + j, ks, l);
#pragma unroll
      for (int i = 0; i < 4; ++i)
#pragma unroll
        for (int j = 0; j < 4; ++j)
          acc[i][j] = __builtin_amdgcn_mfma_f32_16x16x32_bf16(ah[i], bh[j], acc[i][j], 0, 0, 0);
#pragma unroll
      for (int i = 0; i < 4; ++i) x[i] = read_frag(Al, wr * 4 + i, ks, l);
#pragma unroll
      for (int i = 0; i < 4; ++i)
#pragma unroll
        for (int j = 0; j < 4; ++j)
          acc[i][j] = __builtin_amdgcn_mfma_f32_16x16x32_bf16(x[i], bh[j], acc[i][j], 0, 0, 0);
#pragma unroll
      for (int j = 0; j < 4; ++j) x[j] = read_frag(Bl, wc * 4 + j, ks, l);
#pragma unroll
      for (int i = 0; i < 4; ++i)
#pragma unroll
        for (int j = 0; j < 4; ++j)
          acc[i][j] = __builtin_amdgcn_mfma_f32_16x16x32_bf16(ah[i], x[j], acc[i][j], 0, 0, 0);
    }
    __syncthreads();
  }
  float* gout = gram + (size_t)lb * T_DIM * T_DIM;
#pragma unroll
  for (int i = 0; i < 4; ++i) {
    int mrow = m0 + wr * 64 + i * 16 + ((l >> 4) << 2);
#pragma unroll
    for (int j = 0; j < 4; ++j) {
      int ncol = n0 + wc * 64 + j * 16 + (l & 15);
      float* cp = gout + (size_t)mrow * T_DIM + ncol;
#pragma unroll
      for (int r = 0; r < 4; ++r) cp[(size_t)r * T_DIM] = acc[i][j][r];
    }
  }
}

// ---------------- plain bf16 GEMM C = A.B^T (A=Fh 16384xK', B rows of length K) ----------------
__global__ __launch_bounds__(256, 2) void k_gemm16(const __bf16* __restrict__ A,
                                                   const __bf16* __restrict__ Bm,
                                                   float* __restrict__ C, int N, int K,
                                                   int conv, const __bf16* __restrict__ zp) {
  __shared__ __bf16 As[128 * 64], Bs[128 * 64];
  int m0 = blockIdx.y * 128, n0 = blockIdx.x * 128;
  int tid = threadIdx.x, w = tid >> 6, l = tid & 63;
  int wr = w >> 1, wc = w & 1;
  f32x4 acc[4][4];
#pragma unroll
  for (int i = 0; i < 4; ++i)
#pragma unroll
    for (int j = 0; j < 4; ++j) acc[i][j] = {0.f, 0.f, 0.f, 0.f};

  for (int k0 = 0; k0 < K; k0 += 64) {
    if (conv)
      stage_tile_conv(A, m0, k0, zp, As, w, l);
    else
      stage_tile(A, (size_t)m0, C_DIM, k0, As, w, l);
    stage_tile(Bm, (size_t)n0, K, k0, Bs, w, l);
    __syncthreads();
#pragma unroll
    for (int ks = 0; ks < 2; ++ks) {
      bf16x8 af[4], bf_[4];
#pragma unroll
      for (int i = 0; i < 4; ++i) af[i] = read_frag(As, wr * 4 + i, ks, l);
#pragma unroll
      for (int j = 0; j < 4; ++j) bf_[j] = read_frag(Bs, wc * 4 + j, ks, l);
#pragma unroll
      for (int i = 0; i < 4; ++i)
#pragma unroll
        for (int j = 0; j < 4; ++j)
          acc[i][j] = __builtin_amdgcn_mfma_f32_16x16x32_bf16(af[i], bf_[j], acc[i][j], 0, 0, 0);
    }
    __syncthreads();
  }
#pragma unroll
  for (int i = 0; i < 4; ++i) {
    int mrow = m0 + wr * 64 + i * 16 + ((l >> 4) << 2);
#pragma unroll
    for (int j = 0; j < 4; ++j) {
      int ncol = n0 + wc * 64 + j * 16 + (l & 15);
      float* cp = C + (size_t)mrow * N + ncol;
#pragma unroll
      for (int r = 0; r < 4; ++r) cp[(size_t)r * N] = acc[i][j][r];
    }
  }
}

// ---------------- per-row top-10 of dif = sq_i + sq_j - 2*gram[i][j] ----------------
__global__ __launch_bounds__(256) void k_topk(const float* __restrict__ gram,
                                              const float* __restrict__ sq,
                                              int* __restrict__ idxo,
                                              float* __restrict__ wo, int bg) {
  int lb = blockIdx.y;
  const float* gramb = gram + (size_t)lb * T_DIM * T_DIM;
  const float* sqb = sq + (size_t)(bg + lb) * T_DIM;
  int* idxb = idxo + (size_t)(bg + lb) * T_DIM * KNB;
  float* wbp = wo + (size_t)(bg + lb) * T_DIM * KNB;

  int row = blockIdx.x * 4 + (threadIdx.x >> 6);
  int lane = threadIdx.x & 63;
  float sqi = sqb[row];
  const float* g = gramb + (size_t)row * T_DIM;
  unsigned long long a0 = ~0ull, a1 = ~0ull, a2 = ~0ull, a3 = ~0ull, a4 = ~0ull,
                     a5 = ~0ull, a6 = ~0ull, a7 = ~0ull, a8 = ~0ull, a9 = ~0ull;
  for (int j = lane; j < T_DIM; j += 64) {
    float dif = sqi + sqb[j] - 2.0f * g[j];
    unsigned u = __float_as_uint(dif);
    u = (u & 0x80000000u) ? ~u : (u | 0x80000000u);
    unsigned long long key = ((unsigned long long)u << 32) | (unsigned)j;
    if (key < a9) {
      a9 = key;
      unsigned long long t;
      if (a9 < a8) { t = a8; a8 = a9; a9 = t; }
      if (a8 < a7) { t = a7; a7 = a8; a8 = t; }
      if (a7 < a6) { t = a6; a6 = a7; a7 = t; }
      if (a6 < a5) { t = a5; a5 = a6; a6 = t; }
      if (a5 < a4) { t = a4; a4 = a5; a5 = t; }
      if (a4 < a3) { t = a3; a3 = a4; a4 = t; }
      if (a3 < a2) { t = a2; a2 = a3; a3 = t; }
      if (a2 < a1) { t = a1; a1 = a2; a2 = t; }
      if (a1 < a0) { t = a0; a0 = a1; a1 = t; }
    }
  }
#pragma unroll
  for (int s = 0; s < KNB; ++s) {
    unsigned long long h = a0;
    unsigned long long m = h;
#pragma unroll
    for (int d = 1; d < 64; d <<= 1) {
      unsigned long long o = __shfl_xor(m, d, 64);
      m = (o < m) ? o : m;
    }
    unsigned long long bal = __ballot(h == m);
    int leader = (int)__builtin_ctzll(bal);
    if (lane == leader) {
      a0 = a1; a1 = a2; a2 = a3; a3 = a4; a4 = a5;
      a5 = a6; a6 = a7; a7 = a8; a8 = a9; a9 = ~0ull;
    }
    if (lane == 0) {
      int j = (int)(unsigned)(m & 0xffffffffull);
      unsigned su = (unsigned)(m >> 32);
      unsigned bits = (su & 0x80000000u) ? (su & 0x7fffffffu) : ~su;
      float dif = __uint_as_float(bits);
      float sqj = sqb[j];
      float num = 0.5f * (sqi + sqj - dif);
      float wv = num / (sqrtf(sqi) * sqrtf(sqj));
      idxb[row * KNB + s] = j;
      wbp[row * KNB + s] = wv;
    }
  }
}

// ---------------- gmax[n,o] = max_k (P[idx_k,o] + Q[n,o] + mlp_b[o]) * w[n,k] ----------------
// mlpout: [n][512], cols 0..255 = P (neighbor half), 256..511 = Q (center half)
__global__ __launch_bounds__(256) void k_gmax(const float* __restrict__ mlpout,
                                              const float* __restrict__ mlp_b,
                                              const int* __restrict__ idxo,
                                              const float* __restrict__ wo,
                                              float* __restrict__ gmax) {
  int n = blockIdx.x;
  int o = threadIdx.x;
  __shared__ int sj[KNB];
  __shared__ float sw[KNB];
  if (o < KNB) {
    sj[o] = (n & ~(T_DIM - 1)) + idxo[(size_t)n * KNB + o];
    sw[o] = wo[(size_t)n * KNB + o];
  }
  __syncthreads();
  float a = mlpout[(size_t)n * 512 + 256 + o] + mlp_b[o];
  float mx = -3.4e38f;
#pragma unroll
  for (int k = 0; k < KNB; ++k) {
    float v = (mlpout[(size_t)sj[k] * 512 + o] + a) * sw[k];
    mx = fmaxf(mx, v);
  }
  gmax[(size_t)n * C_DIM + o] = mx;
}

// ---------------- out = maxpool2(relu(conv + cb + gmax)), (n,o) -> (b,c,t/2) ----------------
__global__ __launch_bounds__(256) void k_final(const float* __restrict__ convb,
                                               const float* __restrict__ gmax,
                                               const float* __restrict__ cb,
                                               float* __restrict__ out) {
  __shared__ float tile[32][33];
  int b = blockIdx.z;
  int c0 = blockIdx.y * 32;
  int t20 = blockIdx.x * 32;
  int tx = threadIdx.x & 31, ty = threadIdx.x >> 5;
#pragma unroll
  for (int r = 0; r < 4; ++r) {
    int t2 = t20 + ty + 8 * r;
    size_t n = ((size_t)b * T_DIM + 2 * t2) * C_DIM + c0 + tx;
    float bias = cb[c0 + tx];
    float v0 = convb[n] + gmax[n] + bias;
    float v1 = convb[n + C_DIM] + gmax[n + C_DIM] + bias;
    v0 = fmaxf(v0, 0.f);
    v1 = fmaxf(v1, 0.f);
    tile[ty + 8 * r][tx] = fmaxf(v0, v1);
  }
  __syncthreads();
#pragma unroll
  for (int r = 0; r < 4; ++r) {
    int c = c0 + ty + 8 * r;
    out[((size_t)b * C_DIM + c) * (T_DIM / 2) + t20 + tx] = tile[tx][ty + 8 * r];
  }
}

// ---------------- repack conv_w (O,I,3) -> wk3[o][tap*256+i] bf16, + zero page ----------------
__global__ void k_repack_conv(const float* __restrict__ cw, __bf16* __restrict__ wk3,
                              __bf16* __restrict__ zp) {
  int i = blockIdx.x * 256 + threadIdx.x;
  if (i < 3 * C_DIM * C_DIM) {
    int o = i / 768;
    int rem = i - o * 768;
    int tap = rem >> 8;
    int ii = rem & 255;
    wk3[i] = bfbits(f2bf_rn(cw[(size_t)o * 768 + ii * 3 + tap]));
  }
  if (blockIdx.x == 0 && threadIdx.x < 128) zp[threadIdx.x] = bfbits(0);
}

// ---------------- repack mlp_w (256,512) -> mlpB[512][256] bf16 ----------------
__global__ void k_repack_mlp(const float* __restrict__ mw, __bf16* __restrict__ mb) {
  int i = blockIdx.x * 256 + threadIdx.x;
  if (i < 512 * 256) {
    int r = i >> 8;
    int c = i & 255;
    mb[i] = bfbits(f2bf_rn(mw[(size_t)(r & 255) * 512 + ((r >> 8) << 8) + c]));
  }
}

extern "C" void kernel_launch(void* const* d_in, const int* in_sizes, int n_in,
                              void* d_out, int out_size, void* d_ws, size_t ws_size,
                              hipStream_t stream) {
  const float* x = (const float*)d_in[0];
  const float* conv_w = (const float*)d_in[2];
  const float* conv_b = (const float*)d_in[3];
  const float* mlp_w = (const float*)d_in[4];
  const float* mlp_b = (const float*)d_in[5];
  float* out = (float*)d_out;

  char* ws = (char*)d_ws;
  size_t off = 0;
  auto alloc = [&](size_t bytes) -> void* {
    void* p = ws + off;
    off += (bytes + 255) & ~(size_t)255;
    return p;
  };
  // regionA: gram (2 batches) early, mlpout later — both 33554432 bytes
  float* regionA = (float*)alloc((size_t)2 * T_DIM * T_DIM * 4);
  __bf16* Fh = (__bf16*)alloc((size_t)NPTS * C_DIM * 2);
  __bf16* Fl = (__bf16*)alloc((size_t)NPTS * C_DIM * 2);
  float* convout = (float*)alloc((size_t)NPTS * C_DIM * 4);
  float* gmaxb = (float*)alloc((size_t)NPTS * C_DIM * 4);
  float* sq = (float*)alloc((size_t)NPTS * 4);
  int* idxb = (int*)alloc((size_t)NPTS * KNB * 4);
  float* wb = (float*)alloc((size_t)NPTS * KNB * 4);
  __bf16* wk3 = (__bf16*)alloc((size_t)3 * C_DIM * C_DIM * 2);
  __bf16* mlpB = (__bf16*)alloc((size_t)512 * 256 * 2);
  __bf16* zp = (__bf16*)alloc(512);
  float* gram2 = regionA;
  float* mlpout = regionA;

  k_repack_conv<<<dim3(768), 256, 0, stream>>>(conv_w, wk3, zp);
  k_repack_mlp<<<dim3(512), 256, 0, stream>>>(mlp_w, mlpB);
  k_transpose_split<<<dim3(T_DIM / 32, C_DIM / 32, BS), 256, 0, stream>>>(x, Fh, Fl);
  k_sq<<<dim3(NPTS / 4), 256, 0, stream>>>(Fh, Fl, sq);

  for (int g = 0; g < 4; ++g) {
    k_gram<<<dim3(T_DIM / 128, T_DIM / 128, 2), 256, 0, stream>>>(Fh, Fl, gram2, g * 2);
    k_topk<<<dim3(T_DIM / 4, 2), 256, 0, stream>>>(gram2, sq, idxb, wb, g * 2);
  }

  // MLP: N=512 (P | Q). Writes regionA (gram done).
  k_gemm16<<<dim3(512 / 128, NPTS / 128), 256, 0, stream>>>(Fh, mlpB, mlpout, 512, 256, 0, zp);
  // Conv: im2col GEMM, K=768, N=256.
  k_gemm16<<<dim3(256 / 128, NPTS / 128), 256, 0, stream>>>(Fh, wk3, convout, 256, 768, 1, zp);

  k_gmax<<<dim3(NPTS), 256, 0, stream>>>(mlpout, mlp_b, idxb, wb, gmaxb);
  k_final<<<dim3((T_DIM / 2) / 32, C_DIM / 32, BS), 256, 0, stream>>>(convout, gmaxb, conv_b, out);
}

// Round 3
// 197.643 us; speedup vs baseline: 3.9872x; 1.2803x over previous
//
#include <hip/hip_runtime.h>
#include <hip/hip_bf16.h>
#include <cstdint>

#define T_DIM 2048
#define C_DIM 256
#define BS 8
#define NPTS (BS * T_DIM)
#define KNB 10

typedef __bf16 bf16x8 __attribute__((ext_vector_type(8)));
typedef float f32x4 __attribute__((ext_vector_type(4)));

#define AS1 __attribute__((address_space(1)))
#define AS3 __attribute__((address_space(3)))

__device__ __forceinline__ unsigned short f2bf_rn(float f) {
  unsigned u = __float_as_uint(f);
  unsigned r = (u + 0x7FFFu + ((u >> 16) & 1u)) >> 16;
  return (unsigned short)r;
}
__device__ __forceinline__ float bfbits2f(unsigned short h) {
  return __uint_as_float((unsigned)h << 16);
}
__device__ __forceinline__ __bf16 bfbits(unsigned short h) {
  return __builtin_bit_cast(__bf16, h);
}

// ---- stage a 128x64 bf16 tile into XOR-swizzled LDS via global_load_lds ----
// LDS layout: byte(row, colbyte) = row*128 + (colbyte ^ ((row&7)<<4)).
// global_load_lds writes linearly (base + lane*16), so the SOURCE address is
// pre-swizzled: lane l covers row (q*8 + (l>>3)), col elems 8*((l&7)^(l>>3)).
__device__ __forceinline__ void stage_tile(const __bf16* __restrict__ src, size_t row0,
                                           int ld, int k0, __bf16* lds, int w, int l) {
  int kofs = ((l & 7) ^ (l >> 3)) * 8;
  const __bf16* g0 = src + (row0 + (size_t)(l >> 3)) * ld + k0 + kofs;
  __bf16* lbase = lds + (size_t)(w * 4) * 512;
#pragma unroll
  for (int q4 = 0; q4 < 4; ++q4) {
    __builtin_amdgcn_global_load_lds((AS1 void*)(g0 + (size_t)(w * 4 + q4) * 8 * ld),
                                     (AS3 void*)(lbase + q4 * 512), 16, 0, 0);
  }
}

// conv im2col staging: K=768 = 3 taps x 256; row source shifted by tap-1,
// batch-boundary rows read a zero page instead (per-lane address select).
__device__ __forceinline__ void stage_tile_conv(const __bf16* __restrict__ src, int m0,
                                                int k0in, const __bf16* __restrict__ zp,
                                                __bf16* lds, int w, int l) {
  int tap = k0in >> 8;
  int kshift = tap - 1;
  int k0 = k0in & 255;
  int kofs = ((l & 7) ^ (l >> 3)) * 8;
  int mb = m0 & (T_DIM - 1);
#pragma unroll
  for (int q4 = 0; q4 < 4; ++q4) {
    int q = w * 4 + q4;
    int row = q * 8 + (l >> 3);
    int t = mb + row + kshift;
    const __bf16* g = ((unsigned)t < (unsigned)T_DIM)
                          ? (src + (size_t)(m0 + row + kshift) * C_DIM + k0 + kofs)
                          : (zp + kofs);
    __builtin_amdgcn_global_load_lds((AS1 void*)g, (AS3 void*)(lds + q * 512), 16, 0, 0);
  }
}

// fragment read for mfma_f32_16x16x32_bf16: lane holds row (l&15), k-block (l>>4)*8
__device__ __forceinline__ bf16x8 read_frag(const __bf16* lds, int t16, int ks, int l) {
  int row = t16 * 16 + (l & 15);
  int kb = ks * 64 + ((l >> 4) << 4);
  int byte = row * 128 + (kb ^ ((row & 7) << 4));
  return *(const bf16x8*)((const char*)lds + byte);
}

// ---------------- transpose + hi/lo bf16 split: x(b,c,t) -> Fh/Fl[(b*T+t)*C+c] ----------------
__global__ __launch_bounds__(256) void k_transpose_split(const float* __restrict__ x,
                                                         __bf16* __restrict__ Fh,
                                                         __bf16* __restrict__ Fl) {
  __shared__ float tile[32][33];
  int b = blockIdx.z;
  int t0 = blockIdx.x * 32;
  int c0 = blockIdx.y * 32;
  int tx = threadIdx.x & 31, ty = threadIdx.x >> 5;
  const float* xb = x + (size_t)b * C_DIM * T_DIM;
#pragma unroll
  for (int r = 0; r < 4; ++r) {
    int c = c0 + ty + 8 * r;
    tile[ty + 8 * r][tx] = xb[(size_t)c * T_DIM + t0 + tx];
  }
  __syncthreads();
#pragma unroll
  for (int r = 0; r < 4; ++r) {
    int t = t0 + ty + 8 * r;
    float v = tile[tx][ty + 8 * r];
    unsigned short hb = f2bf_rn(v);
    float lo = v - bfbits2f(hb);
    size_t o = ((size_t)b * T_DIM + t) * C_DIM + c0 + tx;
    Fh[o] = bfbits(hb);
    Fl[o] = bfbits(f2bf_rn(lo));
  }
}

// ---------------- sq[n] = sum_c (hi+lo)^2 ----------------
__global__ __launch_bounds__(256) void k_sq(const __bf16* __restrict__ Fh,
                                            const __bf16* __restrict__ Fl,
                                            float* __restrict__ sq) {
  int n = blockIdx.x * 4 + (threadIdx.x >> 6);
  int lane = threadIdx.x & 63;
  ushort4 hv = ((const ushort4*)Fh)[(size_t)n * 64 + lane];
  ushort4 lv = ((const ushort4*)Fl)[(size_t)n * 64 + lane];
  float s = 0.f;
  {
    float v;
    v = bfbits2f(hv.x) + bfbits2f(lv.x); s = fmaf(v, v, s);
    v = bfbits2f(hv.y) + bfbits2f(lv.y); s = fmaf(v, v, s);
    v = bfbits2f(hv.z) + bfbits2f(lv.z); s = fmaf(v, v, s);
    v = bfbits2f(hv.w) + bfbits2f(lv.w); s = fmaf(v, v, s);
  }
#pragma unroll
  for (int d = 1; d < 64; d <<= 1) s += __shfl_xor(s, d, 64);
  if (lane == 0) sq[n] = s;
}

// ---------------- Gram via split-bf16 MFMA, symmetric: only by>=bx blocks ----------------
// Normal epilogue writes [m][n]; mirror epilogue (bx!=by) transposes the tile
// through LDS (reusing staging memory, 64x132-padded) and writes [n][m] coalesced.
__global__ __launch_bounds__(256, 2) void k_gram_sym(const __bf16* __restrict__ Fh,
                                                     const __bf16* __restrict__ Fl,
                                                     float* __restrict__ gram) {
  __shared__ __align__(16) char smem[65536];
  __bf16* Ah = (__bf16*)smem;
  __bf16* Al = (__bf16*)(smem + 16384);
  __bf16* Bh = (__bf16*)(smem + 32768);
  __bf16* Bl = (__bf16*)(smem + 49152);

  int b = blockIdx.y;
  int ti = blockIdx.x;
  // map linear tri-index -> (bx, by) with by >= bx (bx fast within a by-panel)
  int by = (int)((sqrtf(8.0f * (float)ti + 1.0f) - 1.0f) * 0.5f);
  if ((by + 1) * (by + 2) / 2 <= ti) by++;
  int bx = ti - by * (by + 1) / 2;

  size_t base = (size_t)b * T_DIM;
  int m0 = by * 128, n0 = bx * 128;
  int tid = threadIdx.x, w = tid >> 6, l = tid & 63;
  int wr = w >> 1, wc = w & 1;
  f32x4 acc[4][4];
#pragma unroll
  for (int i = 0; i < 4; ++i)
#pragma unroll
    for (int j = 0; j < 4; ++j) acc[i][j] = {0.f, 0.f, 0.f, 0.f};

  for (int k0 = 0; k0 < C_DIM; k0 += 64) {
    stage_tile(Fh, base + m0, C_DIM, k0, Ah, w, l);
    stage_tile(Fl, base + m0, C_DIM, k0, Al, w, l);
    stage_tile(Fh, base + n0, C_DIM, k0, Bh, w, l);
    stage_tile(Fl, base + n0, C_DIM, k0, Bl, w, l);
    __syncthreads();
#pragma unroll
    for (int ks = 0; ks < 2; ++ks) {
      bf16x8 ah[4], bh[4], x[4];
#pragma unroll
      for (int i = 0; i < 4; ++i) ah[i] = read_frag(Ah, wr * 4 + i, ks, l);
#pragma unroll
      for (int j = 0; j < 4; ++j) bh[j] = read_frag(Bh, wc * 4 + j, ks, l);
#pragma unroll
      for (int i = 0; i < 4; ++i)
#pragma unroll
        for (int j = 0; j < 4; ++j)
          acc[i][j] = __builtin_amdgcn_mfma_f32_16x16x32_bf16(ah[i], bh[j], acc[i][j], 0, 0, 0);
#pragma unroll
      for (int i = 0; i < 4; ++i) x[i] = read_frag(Al, wr * 4 + i, ks, l);
#pragma unroll
      for (int i = 0; i < 4; ++i)
#pragma unroll
        for (int j = 0; j < 4; ++j)
          acc[i][j] = __builtin_amdgcn_mfma_f32_16x16x32_bf16(x[i], bh[j], acc[i][j], 0, 0, 0);
#pragma unroll
      for (int j = 0; j < 4; ++j) x[j] = read_frag(Bl, wc * 4 + j, ks, l);
#pragma unroll
      for (int i = 0; i < 4; ++i)
#pragma unroll
        for (int j = 0; j < 4; ++j)
          acc[i][j] = __builtin_amdgcn_mfma_f32_16x16x32_bf16(ah[i], x[j], acc[i][j], 0, 0, 0);
    }
    __syncthreads();
  }

  float* gout = gram + (size_t)b * T_DIM * T_DIM;
  // normal write: rows m0.., cols n0..
#pragma unroll
  for (int i = 0; i < 4; ++i) {
    int mrow = m0 + wr * 64 + i * 16 + ((l >> 4) << 2);
#pragma unroll
    for (int j = 0; j < 4; ++j) {
      int ncol = n0 + wc * 64 + j * 16 + (l & 15);
      float* cp = gout + (size_t)mrow * T_DIM + ncol;
#pragma unroll
      for (int r = 0; r < 4; ++r) cp[(size_t)r * T_DIM] = acc[i][j][r];
    }
  }

  if (bx != by) {
    // mirror write: transpose through LDS in two 64-col halves (pitch 132 floats)
    float* Tbuf = (float*)smem;
#pragma unroll
    for (int h = 0; h < 2; ++h) {
      __syncthreads();
      if (wc == h) {
#pragma unroll
        for (int j = 0; j < 4; ++j) {
          int cH = j * 16 + (l & 15);
          float* dst = Tbuf + cH * 132 + wr * 64 + ((l >> 4) << 2);
#pragma unroll
          for (int i = 0; i < 4; ++i) *(f32x4*)(dst + i * 16) = acc[i][j];
        }
      }
      __syncthreads();
      int cH = tid >> 5;
      int c4 = (tid & 31) * 4;
#pragma unroll
      for (int p = 0; p < 8; ++p) {
        f32x4 v = *(const f32x4*)(Tbuf + (size_t)(p * 8 + cH) * 132 + c4);
        *(f32x4*)(gout + (size_t)(n0 + h * 64 + p * 8 + cH) * T_DIM + m0 + c4) = v;
      }
    }
  }
}

// ---------------- plain bf16 GEMM C = A.B^T ----------------
__global__ __launch_bounds__(256, 2) void k_gemm16(const __bf16* __restrict__ A,
                                                   const __bf16* __restrict__ Bm,
                                                   float* __restrict__ C, int N, int K,
                                                   int conv, const __bf16* __restrict__ zp) {
  __shared__ __bf16 As[128 * 64], Bs[128 * 64];
  int m0 = blockIdx.y * 128, n0 = blockIdx.x * 128;
  int tid = threadIdx.x, w = tid >> 6, l = tid & 63;
  int wr = w >> 1, wc = w & 1;
  f32x4 acc[4][4];
#pragma unroll
  for (int i = 0; i < 4; ++i)
#pragma unroll
    for (int j = 0; j < 4; ++j) acc[i][j] = {0.f, 0.f, 0.f, 0.f};

  for (int k0 = 0; k0 < K; k0 += 64) {
    if (conv)
      stage_tile_conv(A, m0, k0, zp, As, w, l);
    else
      stage_tile(A, (size_t)m0, C_DIM, k0, As, w, l);
    stage_tile(Bm, (size_t)n0, K, k0, Bs, w, l);
    __syncthreads();
#pragma unroll
    for (int ks = 0; ks < 2; ++ks) {
      bf16x8 af[4], bf_[4];
#pragma unroll
      for (int i = 0; i < 4; ++i) af[i] = read_frag(As, wr * 4 + i, ks, l);
#pragma unroll
      for (int j = 0; j < 4; ++j) bf_[j] = read_frag(Bs, wc * 4 + j, ks, l);
#pragma unroll
      for (int i = 0; i < 4; ++i)
#pragma unroll
        for (int j = 0; j < 4; ++j)
          acc[i][j] = __builtin_amdgcn_mfma_f32_16x16x32_bf16(af[i], bf_[j], acc[i][j], 0, 0, 0);
    }
    __syncthreads();
  }
#pragma unroll
  for (int i = 0; i < 4; ++i) {
    int mrow = m0 + wr * 64 + i * 16 + ((l >> 4) << 2);
#pragma unroll
    for (int j = 0; j < 4; ++j) {
      int ncol = n0 + wc * 64 + j * 16 + (l & 15);
      float* cp = C + (size_t)mrow * N + ncol;
#pragma unroll
      for (int r = 0; r < 4; ++r) cp[(size_t)r * N] = acc[i][j][r];
    }
  }
}

// ---------------- per-row top-10 of dif = sq_i + sq_j - 2*gram[i][j] ----------------
__global__ __launch_bounds__(256) void k_topk(const float* __restrict__ gram,
                                              const float* __restrict__ sq,
                                              int* __restrict__ idxo,
                                              float* __restrict__ wo) {
  int lb = blockIdx.y;
  const float* gramb = gram + (size_t)lb * T_DIM * T_DIM;
  const float* sqb = sq + (size_t)lb * T_DIM;
  int* idxb = idxo + (size_t)lb * T_DIM * KNB;
  float* wbp = wo + (size_t)lb * T_DIM * KNB;

  int row = blockIdx.x * 4 + (threadIdx.x >> 6);
  int lane = threadIdx.x & 63;
  float sqi = sqb[row];
  const float* g = gramb + (size_t)row * T_DIM;
  unsigned long long a0 = ~0ull, a1 = ~0ull, a2 = ~0ull, a3 = ~0ull, a4 = ~0ull,
                     a5 = ~0ull, a6 = ~0ull, a7 = ~0ull, a8 = ~0ull, a9 = ~0ull;
  for (int j = lane; j < T_DIM; j += 64) {
    float dif = sqi + sqb[j] - 2.0f * g[j];
    unsigned u = __float_as_uint(dif);
    u = (u & 0x80000000u) ? ~u : (u | 0x80000000u);
    unsigned long long key = ((unsigned long long)u << 32) | (unsigned)j;
    if (key < a9) {
      a9 = key;
      unsigned long long t;
      if (a9 < a8) { t = a8; a8 = a9; a9 = t; }
      if (a8 < a7) { t = a7; a7 = a8; a8 = t; }
      if (a7 < a6) { t = a6; a6 = a7; a7 = t; }
      if (a6 < a5) { t = a5; a5 = a6; a6 = t; }
      if (a5 < a4) { t = a4; a4 = a5; a5 = t; }
      if (a4 < a3) { t = a3; a3 = a4; a4 = t; }
      if (a3 < a2) { t = a2; a2 = a3; a3 = t; }
      if (a2 < a1) { t = a1; a1 = a2; a2 = t; }
      if (a1 < a0) { t = a0; a0 = a1; a1 = t; }
    }
  }
#pragma unroll
  for (int s = 0; s < KNB; ++s) {
    unsigned long long h = a0;
    unsigned long long m = h;
#pragma unroll
    for (int d = 1; d < 64; d <<= 1) {
      unsigned long long o = __shfl_xor(m, d, 64);
      m = (o < m) ? o : m;
    }
    unsigned long long bal = __ballot(h == m);
    int leader = (int)__builtin_ctzll(bal);
    if (lane == leader) {
      a0 = a1; a1 = a2; a2 = a3; a3 = a4; a4 = a5;
      a5 = a6; a6 = a7; a7 = a8; a8 = a9; a9 = ~0ull;
    }
    if (lane == 0) {
      int j = (int)(unsigned)(m & 0xffffffffull);
      unsigned su = (unsigned)(m >> 32);
      unsigned bits = (su & 0x80000000u) ? (su & 0x7fffffffu) : ~su;
      float dif = __uint_as_float(bits);
      float sqj = sqb[j];
      float num = 0.5f * (sqi + sqj - dif);
      float wv = num / (sqrtf(sqi) * sqrtf(sqj));
      idxb[row * KNB + s] = j;
      wbp[row * KNB + s] = wv;
    }
  }
}

// ---------------- fused gmax + conv-bias + relu + pairwise maxpool + transpose ----------------
__global__ __launch_bounds__(256) void k_gfinal(const float* __restrict__ mlpout,
                                                const float* __restrict__ mlp_b,
                                                const int* __restrict__ idxo,
                                                const float* __restrict__ wo,
                                                const float* __restrict__ convb,
                                                const float* __restrict__ cb,
                                                float* __restrict__ out) {
  __shared__ float tile[32][33];
  __shared__ int sj[64][KNB];
  __shared__ float sw[64][KNB];
  int b = blockIdx.z, c0 = blockIdx.y * 32, t20 = blockIdx.x * 32;
  int tid = threadIdx.x;
  int nbase = b * T_DIM + t20 * 2;
  for (int e = tid; e < 64 * KNB; e += 256) {
    int ln = e / KNB, k = e - ln * KNB;
    sj[ln][k] = b * T_DIM + idxo[(size_t)(nbase + ln) * KNB + k];
    sw[ln][k] = wo[(size_t)(nbase + ln) * KNB + k];
  }
  __syncthreads();
  int tx = tid & 31, ty = tid >> 5;
  int c = c0 + tx;
  float bias_c = cb[c];
  float mbias = mlp_b[c];
#pragma unroll
  for (int rr = 0; rr < 4; ++rr) {
    int lt2 = ty + 8 * rr;
    float res[2];
#pragma unroll
    for (int s = 0; s < 2; ++s) {
      int ln = 2 * lt2 + s;
      int n = nbase + ln;
      float q = mlpout[(size_t)n * 512 + 256 + c] + mbias;
      float mx = -3.4e38f;
#pragma unroll
      for (int k = 0; k < KNB; ++k) {
        float v = (mlpout[(size_t)sj[ln][k] * 512 + c] + q) * sw[ln][k];
        mx = fmaxf(mx, v);
      }
      float v = convb[(size_t)n * C_DIM + c] + mx + bias_c;
      res[s] = fmaxf(v, 0.f);
    }
    tile[lt2][tx] = fmaxf(res[0], res[1]);
  }
  __syncthreads();
#pragma unroll
  for (int rr = 0; rr < 4; ++rr) {
    int cc = c0 + ty + 8 * rr;
    out[((size_t)b * C_DIM + cc) * (T_DIM / 2) + t20 + tx] = tile[tx][ty + 8 * rr];
  }
}

// ---------------- merged repack: conv_w -> wk3, mlp_w -> mlpB, zero page ----------------
__global__ void k_repack(const float* __restrict__ cw, const float* __restrict__ mw,
                         __bf16* __restrict__ wk3, __bf16* __restrict__ mlpB,
                         __bf16* __restrict__ zp) {
  int i = blockIdx.x * 256 + threadIdx.x;
  if (i < 3 * C_DIM * C_DIM) {
    int o = i / 768;
    int rem = i - o * 768;
    int tap = rem >> 8;
    int ii = rem & 255;
    wk3[i] = bfbits(f2bf_rn(cw[(size_t)o * 768 + ii * 3 + tap]));
  } else {
    int m = i - 3 * C_DIM * C_DIM;
    if (m < 512 * 256) {
      int r = m >> 8;
      int col = m & 255;
      mlpB[m] = bfbits(f2bf_rn(mw[(size_t)(r & 255) * 512 + ((r >> 8) << 8) + col]));
    }
  }
  if (blockIdx.x == 0 && threadIdx.x < 128) zp[threadIdx.x] = bfbits(0);
}

extern "C" void kernel_launch(void* const* d_in, const int* in_sizes, int n_in,
                              void* d_out, int out_size, void* d_ws, size_t ws_size,
                              hipStream_t stream) {
  const float* x = (const float*)d_in[0];
  const float* conv_w = (const float*)d_in[2];
  const float* conv_b = (const float*)d_in[3];
  const float* mlp_w = (const float*)d_in[4];
  const float* mlp_b = (const float*)d_in[5];
  float* out = (float*)d_out;

  char* ws = (char*)d_ws;
  size_t off = 0;
  auto alloc = [&](size_t bytes) -> void* {
    void* p = ws + off;
    off += (bytes + 255) & ~(size_t)255;
    return p;
  };
  float* gram = (float*)alloc((size_t)BS * T_DIM * T_DIM * 4);   // 134.2 MB
  __bf16* Fh = (__bf16*)alloc((size_t)NPTS * C_DIM * 2);
  __bf16* Fl = (__bf16*)alloc((size_t)NPTS * C_DIM * 2);
  float* convout = (float*)alloc((size_t)NPTS * C_DIM * 4);
  float* mlpout = (float*)alloc((size_t)NPTS * 512 * 4);
  float* sq = (float*)alloc((size_t)NPTS * 4);
  int* idxb = (int*)alloc((size_t)NPTS * KNB * 4);
  float* wb = (float*)alloc((size_t)NPTS * KNB * 4);
  __bf16* wk3 = (__bf16*)alloc((size_t)3 * C_DIM * C_DIM * 2);
  __bf16* mlpB = (__bf16*)alloc((size_t)512 * 256 * 2);
  __bf16* zp = (__bf16*)alloc(512);

  k_repack<<<dim3(1280), 256, 0, stream>>>(conv_w, mlp_w, wk3, mlpB, zp);
  k_transpose_split<<<dim3(T_DIM / 32, C_DIM / 32, BS), 256, 0, stream>>>(x, Fh, Fl);
  k_sq<<<dim3(NPTS / 4), 256, 0, stream>>>(Fh, Fl, sq);

  // symmetric Gram: 136 triangular blocks x 8 batches, one dispatch
  k_gram_sym<<<dim3(136, BS), 256, 0, stream>>>(Fh, Fl, gram);
  // top-10 per row, one dispatch over all batches
  k_topk<<<dim3(T_DIM / 4, BS), 256, 0, stream>>>(gram, sq, idxb, wb);

  // MLP: N=512 (P | Q)
  k_gemm16<<<dim3(512 / 128, NPTS / 128), 256, 0, stream>>>(Fh, mlpB, mlpout, 512, 256, 0, zp);
  // Conv: im2col GEMM, K=768, N=256
  k_gemm16<<<dim3(256 / 128, NPTS / 128), 256, 0, stream>>>(Fh, wk3, convout, 256, 768, 1, zp);

  // fused gmax + conv-bias + relu + pool + transpose
  k_gfinal<<<dim3((T_DIM / 2) / 32, C_DIM / 32, BS), 256, 0, stream>>>(
      mlpout, mlp_b, idxb, wb, convout, conv_b, out);
}

// Round 4
// 189.432 us; speedup vs baseline: 4.1601x; 1.0433x over previous
//
#include <hip/hip_runtime.h>
#include <hip/hip_bf16.h>
#include <cstdint>

#define T_DIM 2048
#define C_DIM 256
#define BS 8
#define NPTS (BS * T_DIM)
#define KNB 10

typedef __bf16 bf16x8 __attribute__((ext_vector_type(8)));
typedef float f32x4 __attribute__((ext_vector_type(4)));

#define AS1 __attribute__((address_space(1)))
#define AS3 __attribute__((address_space(3)))

__device__ __forceinline__ unsigned short f2bf_rn(float f) {
  unsigned u = __float_as_uint(f);
  unsigned r = (u + 0x7FFFu + ((u >> 16) & 1u)) >> 16;
  return (unsigned short)r;
}
__device__ __forceinline__ float bfbits2f(unsigned short h) {
  return __uint_as_float((unsigned)h << 16);
}
__device__ __forceinline__ __bf16 bfbits(unsigned short h) {
  return __builtin_bit_cast(__bf16, h);
}

// ---- stage a 128x64 bf16 tile into XOR-swizzled LDS via global_load_lds ----
__device__ __forceinline__ void stage_tile(const __bf16* __restrict__ src, size_t row0,
                                           int ld, int k0, __bf16* lds, int w, int l) {
  int kofs = ((l & 7) ^ (l >> 3)) * 8;
  const __bf16* g0 = src + (row0 + (size_t)(l >> 3)) * ld + k0 + kofs;
  __bf16* lbase = lds + (size_t)(w * 4) * 512;
#pragma unroll
  for (int q4 = 0; q4 < 4; ++q4) {
    __builtin_amdgcn_global_load_lds((AS1 void*)(g0 + (size_t)(w * 4 + q4) * 8 * ld),
                                     (AS3 void*)(lbase + q4 * 512), 16, 0, 0);
  }
}

// conv im2col staging: K=768 = 3 taps x 256
__device__ __forceinline__ void stage_tile_conv(const __bf16* __restrict__ src, int m0,
                                                int k0in, const __bf16* __restrict__ zp,
                                                __bf16* lds, int w, int l) {
  int tap = k0in >> 8;
  int kshift = tap - 1;
  int k0 = k0in & 255;
  int kofs = ((l & 7) ^ (l >> 3)) * 8;
  int mb = m0 & (T_DIM - 1);
#pragma unroll
  for (int q4 = 0; q4 < 4; ++q4) {
    int q = w * 4 + q4;
    int row = q * 8 + (l >> 3);
    int t = mb + row + kshift;
    const __bf16* g = ((unsigned)t < (unsigned)T_DIM)
                          ? (src + (size_t)(m0 + row + kshift) * C_DIM + k0 + kofs)
                          : (zp + kofs);
    __builtin_amdgcn_global_load_lds((AS1 void*)g, (AS3 void*)(lds + q * 512), 16, 0, 0);
  }
}

__device__ __forceinline__ bf16x8 read_frag(const __bf16* lds, int t16, int ks, int l) {
  int row = t16 * 16 + (l & 15);
  int kb = ks * 64 + ((l >> 4) << 4);
  int byte = row * 128 + (kb ^ ((row & 7) << 4));
  return *(const bf16x8*)((const char*)lds + byte);
}

// ---------------- transpose + hi/lo bf16 split ----------------
__global__ __launch_bounds__(256) void k_transpose_split(const float* __restrict__ x,
                                                         __bf16* __restrict__ Fh,
                                                         __bf16* __restrict__ Fl) {
  __shared__ float tile[32][33];
  int b = blockIdx.z;
  int t0 = blockIdx.x * 32;
  int c0 = blockIdx.y * 32;
  int tx = threadIdx.x & 31, ty = threadIdx.x >> 5;
  const float* xb = x + (size_t)b * C_DIM * T_DIM;
#pragma unroll
  for (int r = 0; r < 4; ++r) {
    int c = c0 + ty + 8 * r;
    tile[ty + 8 * r][tx] = xb[(size_t)c * T_DIM + t0 + tx];
  }
  __syncthreads();
#pragma unroll
  for (int r = 0; r < 4; ++r) {
    int t = t0 + ty + 8 * r;
    float v = tile[tx][ty + 8 * r];
    unsigned short hb = f2bf_rn(v);
    float lo = v - bfbits2f(hb);
    size_t o = ((size_t)b * T_DIM + t) * C_DIM + c0 + tx;
    Fh[o] = bfbits(hb);
    Fl[o] = bfbits(f2bf_rn(lo));
  }
}

// ---------------- sq[n] = sum_c (hi+lo)^2 ----------------
__global__ __launch_bounds__(256) void k_sq(const __bf16* __restrict__ Fh,
                                            const __bf16* __restrict__ Fl,
                                            float* __restrict__ sq) {
  int n = blockIdx.x * 4 + (threadIdx.x >> 6);
  int lane = threadIdx.x & 63;
  ushort4 hv = ((const ushort4*)Fh)[(size_t)n * 64 + lane];
  ushort4 lv = ((const ushort4*)Fl)[(size_t)n * 64 + lane];
  float s = 0.f;
  {
    float v;
    v = bfbits2f(hv.x) + bfbits2f(lv.x); s = fmaf(v, v, s);
    v = bfbits2f(hv.y) + bfbits2f(lv.y); s = fmaf(v, v, s);
    v = bfbits2f(hv.z) + bfbits2f(lv.z); s = fmaf(v, v, s);
    v = bfbits2f(hv.w) + bfbits2f(lv.w); s = fmaf(v, v, s);
  }
#pragma unroll
  for (int d = 1; d < 64; d <<= 1) s += __shfl_xor(s, d, 64);
  if (lane == 0) sq[n] = s;
}

// ---------------- Gram via split-bf16 MFMA, symmetric ----------------
__global__ __launch_bounds__(256, 2) void k_gram_sym(const __bf16* __restrict__ Fh,
                                                     const __bf16* __restrict__ Fl,
                                                     float* __restrict__ gram) {
  __shared__ __align__(16) char smem[65536];
  __bf16* Ah = (__bf16*)smem;
  __bf16* Al = (__bf16*)(smem + 16384);
  __bf16* Bh = (__bf16*)(smem + 32768);
  __bf16* Bl = (__bf16*)(smem + 49152);

  int b = blockIdx.y;
  int ti = blockIdx.x;
  int by = (int)((sqrtf(8.0f * (float)ti + 1.0f) - 1.0f) * 0.5f);
  if ((by + 1) * (by + 2) / 2 <= ti) by++;
  int bx = ti - by * (by + 1) / 2;

  size_t base = (size_t)b * T_DIM;
  int m0 = by * 128, n0 = bx * 128;
  int tid = threadIdx.x, w = tid >> 6, l = tid & 63;
  int wr = w >> 1, wc = w & 1;
  f32x4 acc[4][4];
#pragma unroll
  for (int i = 0; i < 4; ++i)
#pragma unroll
    for (int j = 0; j < 4; ++j) acc[i][j] = {0.f, 0.f, 0.f, 0.f};

  for (int k0 = 0; k0 < C_DIM; k0 += 64) {
    stage_tile(Fh, base + m0, C_DIM, k0, Ah, w, l);
    stage_tile(Fl, base + m0, C_DIM, k0, Al, w, l);
    stage_tile(Fh, base + n0, C_DIM, k0, Bh, w, l);
    stage_tile(Fl, base + n0, C_DIM, k0, Bl, w, l);
    __syncthreads();
#pragma unroll
    for (int ks = 0; ks < 2; ++ks) {
      bf16x8 ah[4], bh[4], x[4];
#pragma unroll
      for (int i = 0; i < 4; ++i) ah[i] = read_frag(Ah, wr * 4 + i, ks, l);
#pragma unroll
      for (int j = 0; j < 4; ++j) bh[j] = read_frag(Bh, wc * 4 + j, ks, l);
#pragma unroll
      for (int i = 0; i < 4; ++i)
#pragma unroll
        for (int j = 0; j < 4; ++j)
          acc[i][j] = __builtin_amdgcn_mfma_f32_16x16x32_bf16(ah[i], bh[j], acc[i][j], 0, 0, 0);
#pragma unroll
      for (int i = 0; i < 4; ++i) x[i] = read_frag(Al, wr * 4 + i, ks, l);
#pragma unroll
      for (int i = 0; i < 4; ++i)
#pragma unroll
        for (int j = 0; j < 4; ++j)
          acc[i][j] = __builtin_amdgcn_mfma_f32_16x16x32_bf16(x[i], bh[j], acc[i][j], 0, 0, 0);
#pragma unroll
      for (int j = 0; j < 4; ++j) x[j] = read_frag(Bl, wc * 4 + j, ks, l);
#pragma unroll
      for (int i = 0; i < 4; ++i)
#pragma unroll
        for (int j = 0; j < 4; ++j)
          acc[i][j] = __builtin_amdgcn_mfma_f32_16x16x32_bf16(ah[i], x[j], acc[i][j], 0, 0, 0);
    }
    __syncthreads();
  }

  float* gout = gram + (size_t)b * T_DIM * T_DIM;
#pragma unroll
  for (int i = 0; i < 4; ++i) {
    int mrow = m0 + wr * 64 + i * 16 + ((l >> 4) << 2);
#pragma unroll
    for (int j = 0; j < 4; ++j) {
      int ncol = n0 + wc * 64 + j * 16 + (l & 15);
      float* cp = gout + (size_t)mrow * T_DIM + ncol;
#pragma unroll
      for (int r = 0; r < 4; ++r) cp[(size_t)r * T_DIM] = acc[i][j][r];
    }
  }

  if (bx != by) {
    float* Tbuf = (float*)smem;
#pragma unroll
    for (int h = 0; h < 2; ++h) {
      __syncthreads();
      if (wc == h) {
#pragma unroll
        for (int j = 0; j < 4; ++j) {
          int cH = j * 16 + (l & 15);
          float* dst = Tbuf + cH * 132 + wr * 64 + ((l >> 4) << 2);
#pragma unroll
          for (int i = 0; i < 4; ++i) *(f32x4*)(dst + i * 16) = acc[i][j];
        }
      }
      __syncthreads();
      int cH = tid >> 5;
      int c4 = (tid & 31) * 4;
#pragma unroll
      for (int p = 0; p < 8; ++p) {
        f32x4 v = *(const f32x4*)(Tbuf + (size_t)(p * 8 + cH) * 132 + c4);
        *(f32x4*)(gout + (size_t)(n0 + h * 64 + p * 8 + cH) * T_DIM + m0 + c4) = v;
      }
    }
  }
}

// ---------------- plain bf16 GEMM C = A.B^T ----------------
__global__ __launch_bounds__(256, 2) void k_gemm16(const __bf16* __restrict__ A,
                                                   const __bf16* __restrict__ Bm,
                                                   float* __restrict__ C, int N, int K,
                                                   int conv, const __bf16* __restrict__ zp) {
  __shared__ __bf16 As[128 * 64], Bs[128 * 64];
  int m0 = blockIdx.y * 128, n0 = blockIdx.x * 128;
  int tid = threadIdx.x, w = tid >> 6, l = tid & 63;
  int wr = w >> 1, wc = w & 1;
  f32x4 acc[4][4];
#pragma unroll
  for (int i = 0; i < 4; ++i)
#pragma unroll
    for (int j = 0; j < 4; ++j) acc[i][j] = {0.f, 0.f, 0.f, 0.f};

  for (int k0 = 0; k0 < K; k0 += 64) {
    if (conv)
      stage_tile_conv(A, m0, k0, zp, As, w, l);
    else
      stage_tile(A, (size_t)m0, C_DIM, k0, As, w, l);
    stage_tile(Bm, (size_t)n0, K, k0, Bs, w, l);
    __syncthreads();
#pragma unroll
    for (int ks = 0; ks < 2; ++ks) {
      bf16x8 af[4], bf_[4];
#pragma unroll
      for (int i = 0; i < 4; ++i) af[i] = read_frag(As, wr * 4 + i, ks, l);
#pragma unroll
      for (int j = 0; j < 4; ++j) bf_[j] = read_frag(Bs, wc * 4 + j, ks, l);
#pragma unroll
      for (int i = 0; i < 4; ++i)
#pragma unroll
        for (int j = 0; j < 4; ++j)
          acc[i][j] = __builtin_amdgcn_mfma_f32_16x16x32_bf16(af[i], bf_[j], acc[i][j], 0, 0, 0);
    }
    __syncthreads();
  }
#pragma unroll
  for (int i = 0; i < 4; ++i) {
    int mrow = m0 + wr * 64 + i * 16 + ((l >> 4) << 2);
#pragma unroll
    for (int j = 0; j < 4; ++j) {
      int ncol = n0 + wc * 64 + j * 16 + (l & 15);
      float* cp = C + (size_t)mrow * N + ncol;
#pragma unroll
      for (int r = 0; r < 4; ++r) cp[(size_t)r * N] = acc[i][j][r];
    }
  }
}

// ---------------- per-row top-10: min-2 filter + exact verify + rare fallback ----------------
// Key semantics identical to R3: u64 key = (flip32(dif) << 32) | j, dif computed as
// sqi + sqb[j] - 2.0f*g[j]. Fast path provably exact when count(key < theta) == 9.
__global__ __launch_bounds__(256) void k_topk(const float* __restrict__ gram,
                                              const float* __restrict__ sq,
                                              int* __restrict__ idxo,
                                              float* __restrict__ wo) {
  int lb = blockIdx.y;
  const float* gramb = gram + (size_t)lb * T_DIM * T_DIM;
  const float* sqb = sq + (size_t)lb * T_DIM;
  int* idxb = idxo + (size_t)lb * T_DIM * KNB;
  float* wbp = wo + (size_t)lb * T_DIM * KNB;

  int row = blockIdx.x * 4 + (threadIdx.x >> 6);
  int lane = threadIdx.x & 63;
  float sqi = sqb[row];
  const float* g = gramb + (size_t)row * T_DIM;

  // Phase 1: branchless per-lane min-2, stash hi-words (j = lane + 64*t implicit)
  unsigned kh[32];
  unsigned long long a0 = ~0ull, a1 = ~0ull;
#pragma unroll
  for (int t = 0; t < 32; ++t) {
    int j = lane + 64 * t;
    float dif = sqi + sqb[j] - 2.0f * g[j];
    unsigned u = __float_as_uint(dif);
    u = (u & 0x80000000u) ? ~u : (u | 0x80000000u);
    kh[t] = u;
    unsigned long long key = ((unsigned long long)u << 32) | (unsigned)j;
    unsigned long long mx = (key > a0) ? key : a0;
    a0 = (key < a0) ? key : a0;
    a1 = (mx < a1) ? mx : a1;
  }

  // Phase 2: 10-round wave extract-min over the 128 candidates; write results
  unsigned long long theta = 0;
#pragma unroll
  for (int s = 0; s < KNB; ++s) {
    unsigned long long m = a0;
#pragma unroll
    for (int d = 1; d < 64; d <<= 1) {
      unsigned long long o = __shfl_xor(m, d, 64);
      m = (o < m) ? o : m;
    }
    unsigned long long bal = __ballot(a0 == m);
    int leader = (int)__builtin_ctzll(bal);
    if (lane == leader) { a0 = a1; a1 = ~0ull; }
    if (lane == 0) {
      int j = (int)(unsigned)(m & 0xffffffffull);
      unsigned su = (unsigned)(m >> 32);
      unsigned bits = (su & 0x80000000u) ? (su & 0x7fffffffu) : ~su;
      float dif = __uint_as_float(bits);
      float sqj = sqb[j];
      float num = 0.5f * (sqi + sqj - dif);
      float wv = num / (sqrtf(sqi) * sqrtf(sqj));
      idxb[row * KNB + s] = j;
      wbp[row * KNB + s] = wv;
    }
    theta = m;
  }

  // Phase 3: exact strict-order count vs theta over the whole row
  unsigned thi = (unsigned)(theta >> 32);
  unsigned tlo = (unsigned)(theta & 0xffffffffull);
  int c = 0;
#pragma unroll
  for (int t = 0; t < 32; ++t) {
    unsigned j = (unsigned)(lane + 64 * t);
    c += (kh[t] < thi) || ((kh[t] == thi) && (j < tlo));
  }
#pragma unroll
  for (int d = 1; d < 64; d <<= 1) c += __shfl_xor(c, d, 64);

  if (c == 9) return;  // provably exact (wave-uniform)

  // Fallback (rare): full sorted-10 insert over stashed keys, then re-extract.
  unsigned long long b0 = ~0ull, b1 = ~0ull, b2 = ~0ull, b3 = ~0ull, b4 = ~0ull,
                     b5 = ~0ull, b6 = ~0ull, b7 = ~0ull, b8 = ~0ull, b9 = ~0ull;
#pragma unroll
  for (int t = 0; t < 32; ++t) {
    unsigned long long key = ((unsigned long long)kh[t] << 32) | (unsigned)(lane + 64 * t);
    if (key < b9) {
      b9 = key;
      unsigned long long tt;
      if (b9 < b8) { tt = b8; b8 = b9; b9 = tt; }
      if (b8 < b7) { tt = b7; b7 = b8; b8 = tt; }
      if (b7 < b6) { tt = b6; b6 = b7; b7 = tt; }
      if (b6 < b5) { tt = b5; b5 = b6; b6 = tt; }
      if (b5 < b4) { tt = b4; b4 = b5; b5 = tt; }
      if (b4 < b3) { tt = b3; b3 = b4; b4 = tt; }
      if (b3 < b2) { tt = b2; b2 = b3; b3 = tt; }
      if (b2 < b1) { tt = b1; b1 = b2; b2 = tt; }
      if (b1 < b0) { tt = b0; b0 = b1; b1 = tt; }
    }
  }
#pragma unroll
  for (int s = 0; s < KNB; ++s) {
    unsigned long long m = b0;
#pragma unroll
    for (int d = 1; d < 64; d <<= 1) {
      unsigned long long o = __shfl_xor(m, d, 64);
      m = (o < m) ? o : m;
    }
    unsigned long long bal = __ballot(b0 == m);
    int leader = (int)__builtin_ctzll(bal);
    if (lane == leader) {
      b0 = b1; b1 = b2; b2 = b3; b3 = b4; b4 = b5;
      b5 = b6; b6 = b7; b7 = b8; b8 = b9; b9 = ~0ull;
    }
    if (lane == 0) {
      int j = (int)(unsigned)(m & 0xffffffffull);
      unsigned su = (unsigned)(m >> 32);
      unsigned bits = (su & 0x80000000u) ? (su & 0x7fffffffu) : ~su;
      float dif = __uint_as_float(bits);
      float sqj = sqb[j];
      float num = 0.5f * (sqi + sqj - dif);
      float wv = num / (sqrtf(sqi) * sqrtf(sqj));
      idxb[row * KNB + s] = j;
      wbp[row * KNB + s] = wv;
    }
  }
}

// ---------------- fused gmax + conv-bias + relu + pairwise maxpool + transpose ----------------
__global__ __launch_bounds__(256) void k_gfinal(const float* __restrict__ mlpout,
                                                const float* __restrict__ mlp_b,
                                                const int* __restrict__ idxo,
                                                const float* __restrict__ wo,
                                                const float* __restrict__ convb,
                                                const float* __restrict__ cb,
                                                float* __restrict__ out) {
  __shared__ float tile[32][33];
  __shared__ int sj[64][KNB];
  __shared__ float sw[64][KNB];
  int b = blockIdx.z, c0 = blockIdx.y * 32, t20 = blockIdx.x * 32;
  int tid = threadIdx.x;
  int nbase = b * T_DIM + t20 * 2;
  for (int e = tid; e < 64 * KNB; e += 256) {
    int ln = e / KNB, k = e - ln * KNB;
    sj[ln][k] = b * T_DIM + idxo[(size_t)(nbase + ln) * KNB + k];
    sw[ln][k] = wo[(size_t)(nbase + ln) * KNB + k];
  }
  __syncthreads();
  int tx = tid & 31, ty = tid >> 5;
  int c = c0 + tx;
  float bias_c = cb[c];
  float mbias = mlp_b[c];
#pragma unroll
  for (int rr = 0; rr < 4; ++rr) {
    int lt2 = ty + 8 * rr;
    float res[2];
#pragma unroll
    for (int s = 0; s < 2; ++s) {
      int ln = 2 * lt2 + s;
      int n = nbase + ln;
      float q = mlpout[(size_t)n * 512 + 256 + c] + mbias;
      float mx = -3.4e38f;
#pragma unroll
      for (int k = 0; k < KNB; ++k) {
        float v = (mlpout[(size_t)sj[ln][k] * 512 + c] + q) * sw[ln][k];
        mx = fmaxf(mx, v);
      }
      float v = convb[(size_t)n * C_DIM + c] + mx + bias_c;
      res[s] = fmaxf(v, 0.f);
    }
    tile[lt2][tx] = fmaxf(res[0], res[1]);
  }
  __syncthreads();
#pragma unroll
  for (int rr = 0; rr < 4; ++rr) {
    int cc = c0 + ty + 8 * rr;
    out[((size_t)b * C_DIM + cc) * (T_DIM / 2) + t20 + tx] = tile[tx][ty + 8 * rr];
  }
}

// ---------------- merged repack ----------------
__global__ void k_repack(const float* __restrict__ cw, const float* __restrict__ mw,
                         __bf16* __restrict__ wk3, __bf16* __restrict__ mlpB,
                         __bf16* __restrict__ zp) {
  int i = blockIdx.x * 256 + threadIdx.x;
  if (i < 3 * C_DIM * C_DIM) {
    int o = i / 768;
    int rem = i - o * 768;
    int tap = rem >> 8;
    int ii = rem & 255;
    wk3[i] = bfbits(f2bf_rn(cw[(size_t)o * 768 + ii * 3 + tap]));
  } else {
    int m = i - 3 * C_DIM * C_DIM;
    if (m < 512 * 256) {
      int r = m >> 8;
      int col = m & 255;
      mlpB[m] = bfbits(f2bf_rn(mw[(size_t)(r & 255) * 512 + ((r >> 8) << 8) + col]));
    }
  }
  if (blockIdx.x == 0 && threadIdx.x < 128) zp[threadIdx.x] = bfbits(0);
}

extern "C" void kernel_launch(void* const* d_in, const int* in_sizes, int n_in,
                              void* d_out, int out_size, void* d_ws, size_t ws_size,
                              hipStream_t stream) {
  const float* x = (const float*)d_in[0];
  const float* conv_w = (const float*)d_in[2];
  const float* conv_b = (const float*)d_in[3];
  const float* mlp_w = (const float*)d_in[4];
  const float* mlp_b = (const float*)d_in[5];
  float* out = (float*)d_out;

  char* ws = (char*)d_ws;
  size_t off = 0;
  auto alloc = [&](size_t bytes) -> void* {
    void* p = ws + off;
    off += (bytes + 255) & ~(size_t)255;
    return p;
  };
  float* gram = (float*)alloc((size_t)BS * T_DIM * T_DIM * 4);
  __bf16* Fh = (__bf16*)alloc((size_t)NPTS * C_DIM * 2);
  __bf16* Fl = (__bf16*)alloc((size_t)NPTS * C_DIM * 2);
  float* convout = (float*)alloc((size_t)NPTS * C_DIM * 4);
  float* mlpout = (float*)alloc((size_t)NPTS * 512 * 4);
  float* sq = (float*)alloc((size_t)NPTS * 4);
  int* idxb = (int*)alloc((size_t)NPTS * KNB * 4);
  float* wb = (float*)alloc((size_t)NPTS * KNB * 4);
  __bf16* wk3 = (__bf16*)alloc((size_t)3 * C_DIM * C_DIM * 2);
  __bf16* mlpB = (__bf16*)alloc((size_t)512 * 256 * 2);
  __bf16* zp = (__bf16*)alloc(512);

  k_repack<<<dim3(1280), 256, 0, stream>>>(conv_w, mlp_w, wk3, mlpB, zp);
  k_transpose_split<<<dim3(T_DIM / 32, C_DIM / 32, BS), 256, 0, stream>>>(x, Fh, Fl);
  k_sq<<<dim3(NPTS / 4), 256, 0, stream>>>(Fh, Fl, sq);

  k_gram_sym<<<dim3(136, BS), 256, 0, stream>>>(Fh, Fl, gram);
  k_topk<<<dim3(T_DIM / 4, BS), 256, 0, stream>>>(gram, sq, idxb, wb);

  k_gemm16<<<dim3(512 / 128, NPTS / 128), 256, 0, stream>>>(Fh, mlpB, mlpout, 512, 256, 0, zp);
  k_gemm16<<<dim3(256 / 128, NPTS / 128), 256, 0, stream>>>(Fh, wk3, convout, 256, 768, 1, zp);

  k_gfinal<<<dim3((T_DIM / 2) / 32, C_DIM / 32, BS), 256, 0, stream>>>(
      mlpout, mlp_b, idxb, wb, convout, conv_b, out);
}